// Round 5
// baseline (251.796 us; speedup 1.0000x reference)
//
#include <hip/hip_runtime.h>

#define N_ROWS 32768
#define D_IN 320
#define CB 16
#define N_BOOKS 8192

typedef __attribute__((ext_vector_type(8))) short bf16x8;
typedef __attribute__((ext_vector_type(4))) float f32x4;
#define MFMA __builtin_amdgcn_mfma_f32_16x16x32_bf16

__device__ __forceinline__ unsigned short bf16rn(float f) {
  unsigned u = __float_as_uint(f);
  u += 0x7fffu + ((u >> 16) & 1u);
  return (unsigned short)(u >> 16);
}
__device__ __forceinline__ float bf16tof(unsigned short h) {
  return __uint_as_float(((unsigned)h) << 16);
}

// ---------------- Kernel 0: prepack codebook into MFMA B-frag image + nh ----------------
// Layout: bfrag[bt][split s][lane][8] shorts (bt = book tile of 16).
// B1=[c1|c1], B2=[c2|c2], B3=[c3|c1] (K=32 packing). nh[j] = -0.5*||c_j||^2 (fp64->fp32).
__global__ __launch_bounds__(256) void prep_kernel(const float* __restrict__ cbk,
                                                   short* __restrict__ bfrag,
                                                   float* __restrict__ nh_g) {
  const int j = blockIdx.x * 256 + threadIdx.x;
  const float4* src = (const float4*)(cbk + (size_t)j * CB);
  float4 a = src[0], b = src[1], c = src[2], d = src[3];
  float ce[16] = {a.x, a.y, a.z, a.w, b.x, b.y, b.z, b.w,
                  c.x, c.y, c.z, c.w, d.x, d.y, d.z, d.w};
  short c1[16], c2[16], c3[16];
  double s = 0.0;
#pragma unroll
  for (int i = 0; i < 16; i++) {
    s += (double)ce[i] * (double)ce[i];
    unsigned short x1 = bf16rn(ce[i]);
    float r1 = ce[i] - bf16tof(x1);
    unsigned short x2 = bf16rn(r1);
    float r2 = r1 - bf16tof(x2);
    unsigned short x3 = bf16rn(r2);
    c1[i] = (short)x1; c2[i] = (short)x2; c3[i] = (short)x3;
  }
  nh_g[j] = (float)(-0.5 * s);
  bf16x8 lo1, hi1, lo2, hi2, lo3, hi3;
#pragma unroll
  for (int i = 0; i < 8; i++) {
    lo1[i] = c1[i]; hi1[i] = c1[i + 8];
    lo2[i] = c2[i]; hi2[i] = c2[i + 8];
    lo3[i] = c3[i]; hi3[i] = c3[i + 8];
  }
  const int bt = j >> 4, n = j & 15;
  short* base = bfrag + (size_t)bt * 3 * 512;  // 3 frags x 64 lanes x 8 shorts
  // frag s at base + s*512 + (q*16+n)*8
  *(bf16x8*)(base + 0 * 512 + (0 * 16 + n) * 8) = lo1;
  *(bf16x8*)(base + 0 * 512 + (1 * 16 + n) * 8) = hi1;
  *(bf16x8*)(base + 0 * 512 + (2 * 16 + n) * 8) = lo1;
  *(bf16x8*)(base + 0 * 512 + (3 * 16 + n) * 8) = hi1;
  *(bf16x8*)(base + 1 * 512 + (0 * 16 + n) * 8) = lo2;
  *(bf16x8*)(base + 1 * 512 + (1 * 16 + n) * 8) = hi2;
  *(bf16x8*)(base + 1 * 512 + (2 * 16 + n) * 8) = lo2;
  *(bf16x8*)(base + 1 * 512 + (3 * 16 + n) * 8) = hi2;
  *(bf16x8*)(base + 2 * 512 + (0 * 16 + n) * 8) = lo3;
  *(bf16x8*)(base + 2 * 512 + (1 * 16 + n) * 8) = hi3;
  *(bf16x8*)(base + 2 * 512 + (2 * 16 + n) * 8) = lo1;
  *(bf16x8*)(base + 2 * 512 + (3 * 16 + n) * 8) = hi1;
}

// ---------------- Kernel 1: targets = X @ W^T (bf16 3-split MFMA, fp64 flush) ----------------
// Epilogue: LDS transpose of C-layout -> write pre-split A-frag data tsplit[row][48 shorts]
// = t1[16] | t2[16] | t3[16].
__global__ __launch_bounds__(256, 2) void proj_kernel(const float* __restrict__ x,
                                                      const float* __restrict__ w,
                                                      short* __restrict__ tsplit) {
  __shared__ __align__(16) short wfrag[3][10][64][8];  // 30720 B
  __shared__ __align__(16) float xs[2][64 * 36];       // 18432 B
  const int tid = threadIdx.x;
  const int lane = tid & 63;
  const int wv = tid >> 6;

  for (int i = tid; i < D_IN * CB; i += 256) {
    int d = i >> 4, o = i & 15;
    float f = w[o * D_IN + d];
    unsigned short h1 = bf16rn(f);
    float r1 = f - bf16tof(h1);
    unsigned short h2 = bf16rn(r1);
    float r2 = r1 - bf16tof(h2);
    unsigned short h3 = bf16rn(r2);
    int c = d >> 5, qq = (d >> 3) & 3, pos = d & 7;
    int ln = qq * 16 + o;
    wfrag[0][c][ln][pos] = (short)h1;
    wfrag[1][c][ln][pos] = (short)h2;
    wfrag[2][c][ln][pos] = (short)h3;
  }

  const float* xblk = x + (size_t)blockIdx.x * 64 * D_IN;
  {
    int row = tid >> 2, k0 = (tid & 3) * 8;
    float4 v0 = *(const float4*)(xblk + row * D_IN + k0);
    float4 v1 = *(const float4*)(xblk + row * D_IN + k0 + 4);
    *(float4*)&xs[0][row * 36 + k0] = v0;
    *(float4*)&xs[0][row * 36 + k0 + 4] = v1;
  }
  __syncthreads();

  const int m = lane & 15, q = lane >> 4;
  double dacc[4] = {0.0, 0.0, 0.0, 0.0};
  for (int c = 0; c < 10; c++) {
    const int buf = c & 1;
    if (c < 9) {
      int row = tid >> 2, k0 = (tid & 3) * 8;
      float4 v0 = *(const float4*)(xblk + row * D_IN + (c + 1) * 32 + k0);
      float4 v1 = *(const float4*)(xblk + row * D_IN + (c + 1) * 32 + k0 + 4);
      *(float4*)&xs[buf ^ 1][row * 36 + k0] = v0;
      *(float4*)&xs[buf ^ 1][row * 36 + k0 + 4] = v1;
    }
    const float* xp = &xs[buf][(wv * 16 + m) * 36 + q * 8];
    float4 xa = *(const float4*)xp;
    float4 xb = *(const float4*)(xp + 4);
    float xe[8] = {xa.x, xa.y, xa.z, xa.w, xb.x, xb.y, xb.z, xb.w};
    bf16x8 a1, a2, a3;
#pragma unroll
    for (int j = 0; j < 8; j++) {
      unsigned short h1 = bf16rn(xe[j]);
      float r1 = xe[j] - bf16tof(h1);
      unsigned short h2 = bf16rn(r1);
      float r2 = r1 - bf16tof(h2);
      unsigned short h3 = bf16rn(r2);
      a1[j] = (short)h1; a2[j] = (short)h2; a3[j] = (short)h3;
    }
    bf16x8 b1 = *(const bf16x8*)wfrag[0][c][lane];
    bf16x8 b2 = *(const bf16x8*)wfrag[1][c][lane];
    bf16x8 b3 = *(const bf16x8*)wfrag[2][c][lane];
    f32x4 g = {0.f, 0.f, 0.f, 0.f};
    g = MFMA(a1, b1, g, 0, 0, 0);
#pragma unroll
    for (int r = 0; r < 4; r++) dacc[r] += (double)g[r];
    g = (f32x4){0.f, 0.f, 0.f, 0.f};
    g = MFMA(a2, b1, g, 0, 0, 0);
    g = MFMA(a1, b2, g, 0, 0, 0);
#pragma unroll
    for (int r = 0; r < 4; r++) dacc[r] += (double)g[r];
    g = (f32x4){0.f, 0.f, 0.f, 0.f};
    g = MFMA(a3, b1, g, 0, 0, 0);
    g = MFMA(a1, b3, g, 0, 0, 0);
    g = MFMA(a2, b2, g, 0, 0, 0);
#pragma unroll
    for (int r = 0; r < 4; r++) dacc[r] += (double)g[r];
    __syncthreads();
  }

  // epilogue: transpose (C-layout -> row-major fp32) via LDS, then split + store tsplit
  float* tl = (float*)xs;  // 64 rows x stride 17 floats (chunk 9 read xs[1]; safe)
#pragma unroll
  for (int r = 0; r < 4; r++) tl[(wv * 16 + q * 4 + r) * 17 + m] = (float)dacc[r];
  __syncthreads();
  {
    int row_l = tid >> 2, p = tid & 3;
    short h1[4], h2[4], h3[4];
#pragma unroll
    for (int i = 0; i < 4; i++) {
      float f = tl[row_l * 17 + p * 4 + i];
      unsigned short a = bf16rn(f);
      float r1 = f - bf16tof(a);
      unsigned short b = bf16rn(r1);
      float r2 = r1 - bf16tof(b);
      unsigned short cc = bf16rn(r2);
      h1[i] = (short)a; h2[i] = (short)b; h3[i] = (short)cc;
    }
    size_t base = (size_t)(blockIdx.x * 64 + row_l) * 48;
    *(short4*)(tsplit + base + p * 4) = make_short4(h1[0], h1[1], h1[2], h1[3]);
    *(short4*)(tsplit + base + 16 + p * 4) = make_short4(h2[0], h2[1], h2[2], h2[3]);
    *(short4*)(tsplit + base + 32 + p * 4) = make_short4(h3[0], h3[1], h3[2], h3[3]);
  }
}

// ---------------- Kernel 2: scores via prepacked frags + fused top-2 argmax ----------------
// argmin d2 == argmax m = t.c - 0.5||c||^2 (nh folded into MFMA C operand).
// grid = 128 row-groups x 4 book-quarters; block 256 = 4 waves; wave: 4 row-tiles (64 rows).
#define SC_H 4
#define SC_SUB 8  // substages of 256 books per block (8*256 = 2048 = 8192/4)

__global__ __launch_bounds__(256, 2) void score_kernel(const short* __restrict__ tsplit,
                                                       const short* __restrict__ bfrag,
                                                       const float* __restrict__ nh_g,
                                                       float4* __restrict__ cand) {
  __shared__ __align__(16) short ldsb[16 * 3 * 64 * 8];  // 49152 B
  __shared__ float ldsnh[256];
  const int tid = threadIdx.x;
  const int lane = tid & 63;
  const int wv = tid >> 6;
  const int m = lane & 15, q = lane >> 4;
  const int rb = blockIdx.x & 127;
  const int h = blockIdx.x >> 7;
  const int rowbase = rb * 256;

  // A-frags from prepacked tsplit: A12 = [t1|t2], A13 = [t1|t3]
  bf16x8 A12[4], A13[4];
#pragma unroll
  for (int rt = 0; rt < 4; rt++) {
    int row = rowbase + wv * 64 + rt * 16 + m;
    const short* tp = tsplit + (size_t)row * 48;
    A12[rt] = *(const bf16x8*)(tp + q * 8);
    A13[rt] = *(const bf16x8*)(tp + q * 8 + ((q >= 2) ? 16 : 0));
  }

  float4 stg[12];
  float nhreg;
  {
    const float4* gs = (const float4*)(bfrag + (size_t)(h * SC_SUB) * 24576);
#pragma unroll
    for (int it = 0; it < 12; it++) stg[it] = gs[it * 256 + tid];
    nhreg = nh_g[h * 2048 + tid];
  }

  float s1[4][4], s2[4][4];
  int i1[4][4];
#pragma unroll
  for (int rt = 0; rt < 4; rt++)
#pragma unroll
    for (int r = 0; r < 4; r++) { s1[rt][r] = -3.4e38f; s2[rt][r] = -3.4e38f; i1[rt][r] = 0; }

  for (int sc = 0; sc < SC_SUB; sc++) {
    __syncthreads();  // prior substage's readers done
#pragma unroll
    for (int it = 0; it < 12; it++) *(float4*)(ldsb + it * 2048 + tid * 8) = stg[it];
    ldsnh[tid] = nhreg;
    if (sc + 1 < SC_SUB) {  // prefetch next substage (latency hidden by compute)
      const float4* gs = (const float4*)(bfrag + (size_t)(h * SC_SUB + sc + 1) * 24576);
#pragma unroll
      for (int it = 0; it < 12; it++) stg[it] = gs[it * 256 + tid];
      nhreg = nh_g[h * 2048 + (sc + 1) * 256 + tid];
    }
    __syncthreads();

    const int scb = h * 2048 + sc * 256 + m;
#pragma unroll 4
    for (int bt = 0; bt < 16; bt++) {
      bf16x8 b1 = *(const bf16x8*)(ldsb + (bt * 3 + 0) * 512 + lane * 8);
      bf16x8 b2 = *(const bf16x8*)(ldsb + (bt * 3 + 1) * 512 + lane * 8);
      bf16x8 b3 = *(const bf16x8*)(ldsb + (bt * 3 + 2) * 512 + lane * 8);
      float nh0 = ldsnh[bt * 16 + m];
      f32x4 ci = {nh0, nh0, nh0, nh0};
      int colv = scb + (bt << 4);
#pragma unroll
      for (int rt = 0; rt < 4; rt++) {
        f32x4 acc = MFMA(A12[rt], b1, ci, 0, 0, 0);
        acc = MFMA(A12[rt], b2, acc, 0, 0, 0);
        acc = MFMA(A13[rt], b3, acc, 0, 0, 0);
#pragma unroll
        for (int r = 0; r < 4; r++) {
          float v = acc[r];
          bool g = v > s1[rt][r];
          s2[rt][r] = g ? s1[rt][r] : fmaxf(s2[rt][r], v);
          s1[rt][r] = fmaxf(s1[rt][r], v);
          i1[rt][r] = g ? colv : i1[rt][r];
        }
      }
    }
  }

  // cross-lane top-2 merge over 16 column-lanes (ties -> min index)
#pragma unroll
  for (int rt = 0; rt < 4; rt++)
#pragma unroll
    for (int r = 0; r < 4; r++) {
      float a1v = s1[rt][r], a2v = s2[rt][r];
      int ai = i1[rt][r];
#pragma unroll
      for (int msk = 1; msk <= 8; msk <<= 1) {
        float o1 = __shfl_xor(a1v, msk);
        float o2 = __shfl_xor(a2v, msk);
        int oi = __shfl_xor(ai, msk);
        if (o1 > a1v) {
          a2v = fmaxf(a1v, o2); a1v = o1; ai = oi;
        } else {
          a2v = fmaxf(a2v, o1);
          if (o1 == a1v && oi < ai) ai = oi;
        }
      }
      if (m == 0) {
        int row = rowbase + wv * 64 + rt * 16 + q * 4 + r;
        cand[(size_t)h * N_ROWS + row] = make_float4(a1v, a2v, __int_as_float(ai), 0.f);
      }
    }
}

// ---------------- Kernel 3: merge quarters; label + near-tie flag ----------------
#define MARGIN_EPS 1.0e-3f

__global__ __launch_bounds__(256) void reduce_kernel(const float4* __restrict__ cand,
                                                     int* __restrict__ out,
                                                     int* __restrict__ flags) {
  int r = blockIdx.x * 256 + threadIdx.x;
  float S1 = -3.4e38f, S2 = -3.4e38f;
  int I = 0;
#pragma unroll
  for (int h = 0; h < SC_H; h++) {  // ascending book ranges + strict '>' => min index
    float4 v = cand[(size_t)h * N_ROWS + r];
    if (v.x > S1) {
      S2 = fmaxf(S1, v.y); S1 = v.x; I = __float_as_int(v.z);
    } else {
      S2 = fmaxf(S2, v.x);
    }
  }
  out[r] = I;
  flags[r] = (S1 - S2 < MARGIN_EPS) ? 1 : 0;
}

// ---------------- Kernel 4: exact fp64 rescore of flagged rows (t from x,W) ----------------
__global__ __launch_bounds__(256) void fallback_kernel(const float* __restrict__ x,
                                                       const float* __restrict__ w,
                                                       const float* __restrict__ codebook,
                                                       const int* __restrict__ flags,
                                                       int* __restrict__ out) {
  __shared__ int fcache[128];
  __shared__ double ps[16][17];
  __shared__ double tsh[16];
  __shared__ double rs[256];
  __shared__ int ri[256];
  const int tid = threadIdx.x;
  const int base = blockIdx.x * 128;
  if (tid < 128) fcache[tid] = flags[base + tid];
  __syncthreads();

  for (int rr = 0; rr < 128; rr++) {
    if (!fcache[rr]) continue;  // block-uniform
    const int row = base + rr;
    {  // exact fp64 t = x_row . W^T  (thread = (o = tid&15, chunk = tid>>4))
      int o = tid & 15, c = tid >> 4;
      double p = 0.0;
      for (int k = 0; k < 20; k++) {
        int d = c * 20 + k;
        p = fma((double)x[(size_t)row * D_IN + d], (double)w[o * D_IN + d], p);
      }
      ps[c][o] = p;
    }
    __syncthreads();
    if (tid < 16) {
      double t = 0.0;
      for (int c = 0; c < 16; c++) t += ps[c][tid];
      tsh[tid] = t;
    }
    __syncthreads();
    double t[16];
#pragma unroll
    for (int i = 0; i < 16; i++) t[i] = tsh[i];
    double bs = -1.0e300;
    int bi = 0;
    for (int j = tid; j < N_BOOKS; j += 256) {
      const float* cp = codebook + (size_t)j * CB;
      double dot = 0.0, cc = 0.0;
#pragma unroll
      for (int i = 0; i < 16; i++) {
        double cv = (double)cp[i];
        dot = fma(t[i], cv, dot);
        cc = fma(cv, cv, cc);
      }
      double mv = dot - 0.5 * cc;
      if (mv > bs) { bs = mv; bi = j; }  // ascending j: first wins
    }
    rs[tid] = bs; ri[tid] = bi;
    __syncthreads();
    for (int s = 128; s > 0; s >>= 1) {
      if (tid < s) {
        double os = rs[tid + s]; int oi = ri[tid + s];
        if (os > rs[tid] || (os == rs[tid] && oi < ri[tid])) { rs[tid] = os; ri[tid] = oi; }
      }
      __syncthreads();
    }
    if (tid == 0) out[row] = ri[0];
    __syncthreads();
  }
}

extern "C" void kernel_launch(void* const* d_in, const int* in_sizes, int n_in,
                              void* d_out, int out_size, void* d_ws, size_t ws_size,
                              hipStream_t stream) {
  (void)in_sizes; (void)n_in; (void)out_size; (void)ws_size;
  const float* x = (const float*)d_in[0];
  // d_in[1] = mask_time_indices: all-ones -> flatten; unused
  const float* w = (const float*)d_in[2];
  const float* codebook = (const float*)d_in[3];

  char* ws = (char*)d_ws;
  short* tsplit = (short*)(ws);                 // 3 MB  (32768 x 48 shorts)
  short* bfrag = (short*)(ws + (3 << 20));      // 1.5 MB (512 bt x 3 x 64 x 8 shorts)
  float* nh_g = (float*)(ws + 4718592);         // 32 KB  @4.5 MB
  float4* cand = (float4*)(ws + (5 << 20));     // 2 MB   (4 x 32768 x 16 B)
  int* flags = (int*)(ws + (7 << 20));          // 128 KB
  int* out = (int*)d_out;

  prep_kernel<<<N_BOOKS / 256, 256, 0, stream>>>(codebook, bfrag, nh_g);
  proj_kernel<<<N_ROWS / 64, 256, 0, stream>>>(x, w, tsplit);
  score_kernel<<<128 * SC_H, 256, 0, stream>>>(tsplit, bfrag, nh_g, cand);
  reduce_kernel<<<N_ROWS / 256, 256, 0, stream>>>(cand, out, flags);
  fallback_kernel<<<N_ROWS / 128, 256, 0, stream>>>(x, w, codebook, flags, out);
}

// Round 6
// 202.325 us; speedup vs baseline: 1.2445x; 1.2445x over previous
//
#include <hip/hip_runtime.h>

#define N_ROWS 32768
#define D_IN 320
#define CB 16
#define N_BOOKS 8192

typedef __attribute__((ext_vector_type(8))) short bf16x8;
typedef __attribute__((ext_vector_type(4))) float f32x4;
#define MFMA __builtin_amdgcn_mfma_f32_16x16x32_bf16
#define AS1 __attribute__((address_space(1)))
#define AS3 __attribute__((address_space(3)))

__device__ __forceinline__ unsigned short bf16rn(float f) {
  unsigned u = __float_as_uint(f);
  u += 0x7fffu + ((u >> 16) & 1u);
  return (unsigned short)(u >> 16);
}
__device__ __forceinline__ float bf16tof(unsigned short h) {
  return __uint_as_float(((unsigned)h) << 16);
}
// async global->LDS, 16B per lane; lds ptr must be wave-uniform base
__device__ __forceinline__ void gload_lds16(const short* g, short* l) {
  __builtin_amdgcn_global_load_lds((const AS1 unsigned int*)g, (AS3 unsigned int*)l, 16, 0, 0);
}

// ---------------- Kernel 0: prepack codebook into MFMA B-frag image + nh ----------------
// bfrag[bt][split s][lane][8] shorts; B1=[c1|c1], B2=[c2|c2], B3=[c3|c1]. nh = -0.5||c||^2.
__global__ __launch_bounds__(256) void prep_kernel(const float* __restrict__ cbk,
                                                   short* __restrict__ bfrag,
                                                   float* __restrict__ nh_g) {
  const int j = blockIdx.x * 256 + threadIdx.x;
  const float4* src = (const float4*)(cbk + (size_t)j * CB);
  float4 a = src[0], b = src[1], c = src[2], d = src[3];
  float ce[16] = {a.x, a.y, a.z, a.w, b.x, b.y, b.z, b.w,
                  c.x, c.y, c.z, c.w, d.x, d.y, d.z, d.w};
  short c1[16], c2[16], c3[16];
  double s = 0.0;
#pragma unroll
  for (int i = 0; i < 16; i++) {
    s += (double)ce[i] * (double)ce[i];
    unsigned short x1 = bf16rn(ce[i]);
    float r1 = ce[i] - bf16tof(x1);
    unsigned short x2 = bf16rn(r1);
    float r2 = r1 - bf16tof(x2);
    unsigned short x3 = bf16rn(r2);
    c1[i] = (short)x1; c2[i] = (short)x2; c3[i] = (short)x3;
  }
  nh_g[j] = (float)(-0.5 * s);
  bf16x8 lo1, hi1, lo2, hi2, lo3, hi3;
#pragma unroll
  for (int i = 0; i < 8; i++) {
    lo1[i] = c1[i]; hi1[i] = c1[i + 8];
    lo2[i] = c2[i]; hi2[i] = c2[i + 8];
    lo3[i] = c3[i]; hi3[i] = c3[i + 8];
  }
  const int bt = j >> 4, n = j & 15;
  short* base = bfrag + (size_t)bt * 1536;
  *(bf16x8*)(base + 0 * 512 + (0 * 16 + n) * 8) = lo1;
  *(bf16x8*)(base + 0 * 512 + (1 * 16 + n) * 8) = hi1;
  *(bf16x8*)(base + 0 * 512 + (2 * 16 + n) * 8) = lo1;
  *(bf16x8*)(base + 0 * 512 + (3 * 16 + n) * 8) = hi1;
  *(bf16x8*)(base + 1 * 512 + (0 * 16 + n) * 8) = lo2;
  *(bf16x8*)(base + 1 * 512 + (1 * 16 + n) * 8) = hi2;
  *(bf16x8*)(base + 1 * 512 + (2 * 16 + n) * 8) = lo2;
  *(bf16x8*)(base + 1 * 512 + (3 * 16 + n) * 8) = hi2;
  *(bf16x8*)(base + 2 * 512 + (0 * 16 + n) * 8) = lo3;
  *(bf16x8*)(base + 2 * 512 + (1 * 16 + n) * 8) = hi3;
  *(bf16x8*)(base + 2 * 512 + (2 * 16 + n) * 8) = lo1;
  *(bf16x8*)(base + 2 * 512 + (3 * 16 + n) * 8) = hi1;
}

// ---------------- Kernel 1: targets = X @ W^T (bf16 3-split MFMA, fp64 flush) ----------------
// Epilogue: LDS transpose -> tsplit[row][48] = t1[16] | t2[16] | t3[16] (pre-split A data).
__global__ __launch_bounds__(256, 2) void proj_kernel(const float* __restrict__ x,
                                                      const float* __restrict__ w,
                                                      short* __restrict__ tsplit) {
  __shared__ __align__(16) short wfrag[3][10][64][8];  // 30720 B
  __shared__ __align__(16) float xs[2][64 * 36];       // 18432 B
  const int tid = threadIdx.x;
  const int lane = tid & 63;
  const int wv = tid >> 6;

  for (int i = tid; i < D_IN * CB; i += 256) {
    int d = i >> 4, o = i & 15;
    float f = w[o * D_IN + d];
    unsigned short h1 = bf16rn(f);
    float r1 = f - bf16tof(h1);
    unsigned short h2 = bf16rn(r1);
    float r2 = r1 - bf16tof(h2);
    unsigned short h3 = bf16rn(r2);
    int c = d >> 5, qq = (d >> 3) & 3, pos = d & 7;
    int ln = qq * 16 + o;
    wfrag[0][c][ln][pos] = (short)h1;
    wfrag[1][c][ln][pos] = (short)h2;
    wfrag[2][c][ln][pos] = (short)h3;
  }

  const float* xblk = x + (size_t)blockIdx.x * 64 * D_IN;
  {
    int row = tid >> 2, k0 = (tid & 3) * 8;
    float4 v0 = *(const float4*)(xblk + row * D_IN + k0);
    float4 v1 = *(const float4*)(xblk + row * D_IN + k0 + 4);
    *(float4*)&xs[0][row * 36 + k0] = v0;
    *(float4*)&xs[0][row * 36 + k0 + 4] = v1;
  }
  __syncthreads();

  const int m = lane & 15, q = lane >> 4;
  double dacc[4] = {0.0, 0.0, 0.0, 0.0};
  for (int c = 0; c < 10; c++) {
    const int buf = c & 1;
    if (c < 9) {
      int row = tid >> 2, k0 = (tid & 3) * 8;
      float4 v0 = *(const float4*)(xblk + row * D_IN + (c + 1) * 32 + k0);
      float4 v1 = *(const float4*)(xblk + row * D_IN + (c + 1) * 32 + k0 + 4);
      *(float4*)&xs[buf ^ 1][row * 36 + k0] = v0;
      *(float4*)&xs[buf ^ 1][row * 36 + k0 + 4] = v1;
    }
    const float* xp = &xs[buf][(wv * 16 + m) * 36 + q * 8];
    float4 xa = *(const float4*)xp;
    float4 xb = *(const float4*)(xp + 4);
    float xe[8] = {xa.x, xa.y, xa.z, xa.w, xb.x, xb.y, xb.z, xb.w};
    bf16x8 a1, a2, a3;
#pragma unroll
    for (int j = 0; j < 8; j++) {
      unsigned short h1 = bf16rn(xe[j]);
      float r1 = xe[j] - bf16tof(h1);
      unsigned short h2 = bf16rn(r1);
      float r2 = r1 - bf16tof(h2);
      unsigned short h3 = bf16rn(r2);
      a1[j] = (short)h1; a2[j] = (short)h2; a3[j] = (short)h3;
    }
    bf16x8 b1 = *(const bf16x8*)wfrag[0][c][lane];
    bf16x8 b2 = *(const bf16x8*)wfrag[1][c][lane];
    bf16x8 b3 = *(const bf16x8*)wfrag[2][c][lane];
    f32x4 g = {0.f, 0.f, 0.f, 0.f};
    g = MFMA(a1, b1, g, 0, 0, 0);
#pragma unroll
    for (int r = 0; r < 4; r++) dacc[r] += (double)g[r];
    g = (f32x4){0.f, 0.f, 0.f, 0.f};
    g = MFMA(a2, b1, g, 0, 0, 0);
    g = MFMA(a1, b2, g, 0, 0, 0);
#pragma unroll
    for (int r = 0; r < 4; r++) dacc[r] += (double)g[r];
    g = (f32x4){0.f, 0.f, 0.f, 0.f};
    g = MFMA(a3, b1, g, 0, 0, 0);
    g = MFMA(a1, b3, g, 0, 0, 0);
    g = MFMA(a2, b2, g, 0, 0, 0);
#pragma unroll
    for (int r = 0; r < 4; r++) dacc[r] += (double)g[r];
    __syncthreads();
  }

  float* tl = (float*)xs;  // 64 rows x stride 17
#pragma unroll
  for (int r = 0; r < 4; r++) tl[(wv * 16 + q * 4 + r) * 17 + m] = (float)dacc[r];
  __syncthreads();
  {
    int row_l = tid >> 2, p = tid & 3;
    short h1[4], h2[4], h3[4];
#pragma unroll
    for (int i = 0; i < 4; i++) {
      float f = tl[row_l * 17 + p * 4 + i];
      unsigned short a = bf16rn(f);
      float r1 = f - bf16tof(a);
      unsigned short b = bf16rn(r1);
      float r2 = r1 - bf16tof(b);
      unsigned short cc = bf16rn(r2);
      h1[i] = (short)a; h2[i] = (short)b; h3[i] = (short)cc;
    }
    size_t base = (size_t)(blockIdx.x * 64 + row_l) * 48;
    *(short4*)(tsplit + base + p * 4) = make_short4(h1[0], h1[1], h1[2], h1[3]);
    *(short4*)(tsplit + base + 16 + p * 4) = make_short4(h2[0], h2[1], h2[2], h2[3]);
    *(short4*)(tsplit + base + 32 + p * 4) = make_short4(h3[0], h3[1], h3[2], h3[3]);
  }
}

// ---------------- Kernel 2: scores via prepacked frags, async LDS dbuf, top-2 argmax ----------
// grid = 128 row-groups x 4 quarters; block 256 = 4 waves; wave: 4 row-tiles (64 rows).
// Substage = 8 book-tiles (24 KB) double-buffered via global_load_lds; nh staged once (8 KB).
#define SC_H 4

__global__ __launch_bounds__(256, 2) void score_kernel(const short* __restrict__ tsplit,
                                                       const short* __restrict__ bfrag,
                                                       const float* __restrict__ nh_g,
                                                       float4* __restrict__ cand) {
  __shared__ __align__(16) short ldsb[2][12288];  // 2 x 24 KB
  __shared__ float ldsnh[2048];                   // 8 KB
  const int tid = threadIdx.x;
  const int lane = tid & 63;
  const int wv = tid >> 6;
  const int m = lane & 15, q = lane >> 4;
  const int rb = blockIdx.x & 127;
  const int h = blockIdx.x >> 7;
  const int rowbase = rb * 256;

  // A-frags from prepacked tsplit: A12 = [t1|t2], A13 = [t1|t3]
  bf16x8 A12[4], A13[4];
#pragma unroll
  for (int rt = 0; rt < 4; rt++) {
    int row = rowbase + wv * 64 + rt * 16 + m;
    const short* tp = tsplit + (size_t)row * 48;
    A12[rt] = *(const bf16x8*)(tp + q * 8);
    A13[rt] = *(const bf16x8*)(tp + q * 8 + ((q >= 2) ? 16 : 0));
  }
  for (int i = tid; i < 2048; i += 256) ldsnh[i] = nh_g[h * 2048 + i];

  const short* gq = bfrag + (size_t)h * 196608;  // this quarter's frag stream
  {  // stage substage 0
    const short* g0 = gq + wv * 512 + lane * 8;
#pragma unroll
    for (int it = 0; it < 6; it++)
      gload_lds16(g0 + it * 2048, &ldsb[0][it * 2048 + wv * 512]);
  }

  float s1[4][4], s2[4][4];
  int i1[4][4];
#pragma unroll
  for (int rt = 0; rt < 4; rt++)
#pragma unroll
    for (int r = 0; r < 4; r++) { s1[rt][r] = -3.4e38f; s2[rt][r] = -3.4e38f; i1[rt][r] = 0; }

  __syncthreads();  // drains substage-0 loads + nh writes

  for (int sc = 0; sc < 16; sc++) {
    const int cur = sc & 1;
    if (sc < 15) {  // async prefetch next substage into other buffer
      const short* gs = gq + (sc + 1) * 12288 + wv * 512 + lane * 8;
#pragma unroll
      for (int it = 0; it < 6; it++)
        gload_lds16(gs + it * 2048, &ldsb[cur ^ 1][it * 2048 + wv * 512]);
    }
#pragma unroll
    for (int bt = 0; bt < 8; bt++) {
      const short* bp = &ldsb[cur][bt * 1536];
      bf16x8 b1 = *(const bf16x8*)(bp + 0 * 512 + lane * 8);
      bf16x8 b2 = *(const bf16x8*)(bp + 1 * 512 + lane * 8);
      bf16x8 b3 = *(const bf16x8*)(bp + 2 * 512 + lane * 8);
      const int btg = sc * 8 + bt;
      float nh0 = ldsnh[btg * 16 + m];
      f32x4 ci = {nh0, nh0, nh0, nh0};
      const int colv = h * 2048 + btg * 16 + m;
#pragma unroll
      for (int rt = 0; rt < 4; rt++) {
        f32x4 acc = MFMA(A12[rt], b1, ci, 0, 0, 0);
        acc = MFMA(A12[rt], b2, acc, 0, 0, 0);
        acc = MFMA(A13[rt], b3, acc, 0, 0, 0);
#pragma unroll
        for (int r = 0; r < 4; r++) {
          float v = acc[r];
          float s1o = s1[rt][r];
          s2[rt][r] = __builtin_amdgcn_fmed3f(v, s1o, s2[rt][r]);  // new 2nd-best
          s1[rt][r] = fmaxf(s1o, v);
          i1[rt][r] = (v > s1o) ? colv : i1[rt][r];  // strict: earlier bt wins ties
        }
      }
    }
    __syncthreads();  // readers done with cur; prefetch into cur^1 drained
  }

  // cross-lane top-2 merge over 16 column-lanes (ties -> min index)
#pragma unroll
  for (int rt = 0; rt < 4; rt++)
#pragma unroll
    for (int r = 0; r < 4; r++) {
      float a1v = s1[rt][r], a2v = s2[rt][r];
      int ai = i1[rt][r];
#pragma unroll
      for (int msk = 1; msk <= 8; msk <<= 1) {
        float o1 = __shfl_xor(a1v, msk);
        float o2 = __shfl_xor(a2v, msk);
        int oi = __shfl_xor(ai, msk);
        if (o1 > a1v) {
          a2v = fmaxf(a1v, o2); a1v = o1; ai = oi;
        } else {
          a2v = fmaxf(a2v, o1);
          if (o1 == a1v && oi < ai) ai = oi;
        }
      }
      if (m == 0) {
        int row = rowbase + wv * 64 + rt * 16 + q * 4 + r;
        cand[(size_t)h * N_ROWS + row] = make_float4(a1v, a2v, __int_as_float(ai), 0.f);
      }
    }
}

// ---------------- Kernel 3: merge quarters + exact fp64 rescore of near-ties ----------------
#define MARGIN_EPS 1.0e-4f

__global__ __launch_bounds__(256) void reduce_fb_kernel(const float4* __restrict__ cand,
                                                        const float* __restrict__ x,
                                                        const float* __restrict__ w,
                                                        const float* __restrict__ codebook,
                                                        int* __restrict__ out) {
  __shared__ int flagged[256];
  __shared__ double ps[16][17];
  __shared__ double tsh[16];
  __shared__ double rs[256];
  __shared__ int ri[256];
  const int tid = threadIdx.x;
  const int base = blockIdx.x * 256;
  {  // merge 4 quarters (ascending + strict '>' => min index on ties)
    const int r = base + tid;
    float S1 = -3.4e38f, S2 = -3.4e38f;
    int I = 0;
#pragma unroll
    for (int h = 0; h < SC_H; h++) {
      float4 v = cand[(size_t)h * N_ROWS + r];
      if (v.x > S1) {
        S2 = fmaxf(S1, v.y); S1 = v.x; I = __float_as_int(v.z);
      } else {
        S2 = fmaxf(S2, v.x);
      }
    }
    out[r] = I;
    flagged[tid] = (S1 - S2 < MARGIN_EPS) ? 1 : 0;
  }
  __syncthreads();

  for (int rr = 0; rr < 256; rr++) {
    if (!flagged[rr]) continue;  // block-uniform
    const int row = base + rr;
    {  // exact fp64 t = x_row . W^T
      int o = tid & 15, c = tid >> 4;
      double p = 0.0;
      for (int k = 0; k < 20; k++) {
        int d = c * 20 + k;
        p = fma((double)x[(size_t)row * D_IN + d], (double)w[o * D_IN + d], p);
      }
      ps[c][o] = p;
    }
    __syncthreads();
    if (tid < 16) {
      double t = 0.0;
      for (int c = 0; c < 16; c++) t += ps[c][tid];
      tsh[tid] = t;
    }
    __syncthreads();
    double t[16];
#pragma unroll
    for (int i = 0; i < 16; i++) t[i] = tsh[i];
    double bs = -1.0e300;
    int bi = 0;
    for (int j = tid; j < N_BOOKS; j += 256) {
      const float* cp = codebook + (size_t)j * CB;
      double dot = 0.0, cc = 0.0;
#pragma unroll
      for (int i = 0; i < 16; i++) {
        double cv = (double)cp[i];
        dot = fma(t[i], cv, dot);
        cc = fma(cv, cv, cc);
      }
      double mv = dot - 0.5 * cc;
      if (mv > bs) { bs = mv; bi = j; }  // ascending j: first wins
    }
    rs[tid] = bs; ri[tid] = bi;
    __syncthreads();
    for (int s = 128; s > 0; s >>= 1) {
      if (tid < s) {
        double os = rs[tid + s]; int oi = ri[tid + s];
        if (os > rs[tid] || (os == rs[tid] && oi < ri[tid])) { rs[tid] = os; ri[tid] = oi; }
      }
      __syncthreads();
    }
    if (tid == 0) out[row] = ri[0];
    __syncthreads();
  }
}

extern "C" void kernel_launch(void* const* d_in, const int* in_sizes, int n_in,
                              void* d_out, int out_size, void* d_ws, size_t ws_size,
                              hipStream_t stream) {
  (void)in_sizes; (void)n_in; (void)out_size; (void)ws_size;
  const float* x = (const float*)d_in[0];
  // d_in[1] = mask_time_indices: all-ones -> flatten; unused
  const float* w = (const float*)d_in[2];
  const float* codebook = (const float*)d_in[3];

  char* ws = (char*)d_ws;
  short* tsplit = (short*)(ws);              // 3 MB   (32768 x 48 shorts)
  short* bfrag = (short*)(ws + (3 << 20));   // 1.5 MB (512 bt x 1536 shorts)
  float* nh_g = (float*)(ws + 4718592);      // 32 KB
  float4* cand = (float4*)(ws + (5 << 20));  // 2 MB   (4 x 32768 x 16 B)
  int* out = (int*)d_out;

  prep_kernel<<<N_BOOKS / 256, 256, 0, stream>>>(codebook, bfrag, nh_g);
  proj_kernel<<<N_ROWS / 64, 256, 0, stream>>>(x, w, tsplit);
  score_kernel<<<128 * SC_H, 256, 0, stream>>>(tsplit, bfrag, nh_g, cand);
  reduce_fb_kernel<<<N_ROWS / 256, 256, 0, stream>>>(cand, x, w, codebook, out);
}